// Round 7
// baseline (173.798 us; speedup 1.0000x reference)
//
#include <hip/hip_runtime.h>

#define NROWS      100000
#define NUM_CATES  100000
#define MAX_NGH    16
#define MAX_SCENES 10
#define EPSF       1e-10f
#define NTILES     3125

typedef float4 f4;
typedef _Float16 h2 __attribute__((ext_vector_type(2)));
typedef _Float16 h4 __attribute__((ext_vector_type(4)));
typedef _Float16 h8 __attribute__((ext_vector_type(8)));
typedef float f32x4 __attribute__((ext_vector_type(4)));

#if __has_builtin(__builtin_amdgcn_fdot2)
#define FDOT2(a, b, c) __builtin_amdgcn_fdot2((a), (b), (c), false)
#else
#define FDOT2(a, b, c) (fmaf((float)(a).x, (float)(b).x, fmaf((float)(a).y, (float)(b).y, (c))))
#endif

#if __has_builtin(__builtin_amdgcn_rcpf)
#define FRCP(x) __builtin_amdgcn_rcpf(x)
#else
#define FRCP(x) (1.0f / (x))
#endif

__device__ __forceinline__ h2 bc2(unsigned int u) { return __builtin_bit_cast(h2, u); }
__device__ __forceinline__ unsigned int cb2(h2 v) { return __builtin_bit_cast(unsigned int, v); }

// ---- fused build ----
// blocks [0,3125): cate_emb f32 -> h4
// blocks [3125,6250): rowsum -> rs_h + nrm
// block 6250: pack W into MFMA B-fragment order
__global__ __launch_bounds__(512) void build_kernel(
    const float* __restrict__ W,          // [64,128]
    const float* __restrict__ cate_emb,   // [N,64] f32
    const float* __restrict__ scene_emb,  // [5001,64] f32
    const int*   __restrict__ csp,        // [N,10]
    h4*          __restrict__ cate_h,     // [N*16] h4
    h4*          __restrict__ rs_h,       // [N*16] h4
    float*       __restrict__ nrm,        // [N]
    h8*          __restrict__ Wb)         // [1024] h8 fragments
{
    const int b = blockIdx.x, tid = threadIdx.x;
    if (b < 3125) {
        int i = b * 512 + tid;                    // f4 index, 1,600,000 exact
        f4 v = ((const f4*)cate_emb)[i];
        h4 o = {(_Float16)v.x, (_Float16)v.y, (_Float16)v.z, (_Float16)v.w};
        cate_h[i] = o;
    } else if (b < 6250) {
        const int lane = tid & 63;
        const int l16  = lane & 15;
        const int row  = (b - 3125) * 32 + (tid >> 6) * 4 + (lane >> 4);

        int sidx = csp[row * MAX_SCENES + (l16 < 9 ? l16 : 9)];
        const f4* scene4 = (const f4*)scene_emb;
        f4 a[MAX_SCENES];
#pragma unroll
        for (int k = 0; k < MAX_SCENES; ++k)
            a[k] = scene4[__shfl(sidx, k, 16) * 16 + l16];
        f4 s = {0.f, 0.f, 0.f, 0.f};
#pragma unroll
        for (int k = 0; k < MAX_SCENES; ++k) {
            s.x += a[k].x; s.y += a[k].y; s.z += a[k].z; s.w += a[k].w;
        }
        float n2 = s.x * s.x + s.y * s.y + s.z * s.z + s.w * s.w;
#pragma unroll
        for (int off = 1; off < 16; off <<= 1) n2 += __shfl_xor(n2, off);

        h4 hv = {(_Float16)s.x, (_Float16)s.y, (_Float16)s.z, (_Float16)s.w};
        rs_h[row * 16 + l16] = hv;
        if (l16 == 0) nrm[row] = n2;
    } else {
        // B-fragment pack: lane l of fragment u holds W[d][k], d = ch*32+t*16+(l&15),
        // k = ks*32 + (l>>4)*8 + j
#pragma unroll
        for (int u = tid; u < 1024; u += 512) {
            int l  = u & 63;
            int t  = (u >> 6) & 1;
            int ks = (u >> 7) & 3;
            int ch = (u >> 9) & 1;
            int d  = ch * 32 + t * 16 + (l & 15);
            int k0 = ks * 32 + (l >> 4) * 8;
            h8 f;
#pragma unroll
            for (int j = 0; j < 8; ++j) f[j] = (_Float16)W[d * 128 + k0 + j];
            Wb[u] = f;
        }
    }
}

// ---- main: persistent grid-stride, 8 lanes/row sim+agg, MFMA dense, ELU ----
__global__ __launch_bounds__(256, 4) void main_kernel(
    const uint4* __restrict__ rs4,        // rs_h as [N*8] uint4
    const uint4* __restrict__ cate4,      // cate_h as [N*8] uint4
    const float* __restrict__ nrm,        // [N]
    const int2*  __restrict__ ccp2,       // ccp as [N*8] int2
    const h8*    __restrict__ Wb,         // [1024]
    const float* __restrict__ bias,       // [64]
    float*       __restrict__ out)        // [N,64]
{
    __shared__ _Float16 hsh[2][32 * 136]; // double-buffered: 1 barrier per tile

    const int tid  = threadIdx.x;
    const int wave = tid >> 6;
    const int lane = tid & 63;
    const int l8   = lane & 7;
    const int rl   = wave * 8 + (lane >> 3);      // local row 0..31
    const int ch   = wave & 1;                    // col half (32 dims)
    const int r0   = (wave >> 1) * 16;            // local row base of MFMA slab
    const int m    = lane & 15, q = lane >> 4;

    // loop-invariant: B-fragments + bias
    h8 bf[8];
#pragma unroll
    for (int ks = 0; ks < 4; ++ks) {
        bf[2 * ks]     = Wb[((ch * 4 + ks) * 2 + 0) * 64 + lane];
        bf[2 * ks + 1] = Wb[((ch * 4 + ks) * 2 + 1) * 64 + lane];
    }
    const float bv0 = bias[ch * 32 + m];
    const float bv1 = bias[ch * 32 + 16 + m];

    int buf = 0;
    for (int t = blockIdx.x; t < NTILES; t += gridDim.x) {
        const int row = t * 32 + rl;

        int2 nn = ccp2[row * 8 + l8];
        int idx[1 + MAX_NGH];
        idx[0] = row;
#pragma unroll
        for (int j = 1; j <= MAX_NGH; ++j)
            idx[j] = __shfl((j & 1) ? nn.x : nn.y, (j - 1) >> 1, 8);

        uint4 rv[1 + MAX_NGH];
#pragma unroll
        for (int j = 0; j <= MAX_NGH; ++j) rv[j] = rs4[idx[j] * 8 + l8];

        float m0 = nrm[nn.x], m1 = nrm[nn.y];
        float ns = nrm[row] + EPSF;
        float ns_inv = FRCP(ns);

        h2 s0 = bc2(rv[0].x), s1 = bc2(rv[0].y), s2 = bc2(rv[0].z), s3 = bc2(rv[0].w);

        float dotp[1 + MAX_NGH];
#pragma unroll
        for (int j = 0; j <= MAX_NGH; ++j) {
            dotp[j] = FDOT2(s0, bc2(rv[j].x),
                      FDOT2(s1, bc2(rv[j].y),
                      FDOT2(s2, bc2(rv[j].z),
                      FDOT2(s3, bc2(rv[j].w), 0.f))));
        }

        uint4 cv[1 + MAX_NGH];
#pragma unroll
        for (int j = 0; j <= MAX_NGH; ++j) cv[j] = cate4[idx[j] * 8 + l8];

        float miu[1 + MAX_NGH];
        float summiu = 0.f;
#pragma unroll
        for (int j = 0; j <= MAX_NGH; ++j) {
            float d = dotp[j];
            d += __shfl_xor(d, 1); d += __shfl_xor(d, 2); d += __shfl_xor(d, 4);
            float rr = (j == 0) ? (ns - EPSF) : __shfl((j & 1) ? m0 : m1, (j - 1) >> 1, 8);
            bool msk = idx[j] < (NUM_CATES - 1);
            float mu = msk ? __expf(d * ns_inv * FRCP(rr + EPSF)) : 0.f;
            miu[j] = mu;
            summiu += mu;
        }

        const float inv = FRCP(summiu + EPSF);
        const _Float16 z16 = (_Float16)0.f;
        h2 a0 = {z16, z16}, a1 = a0, a2 = a0, a3 = a0;
#pragma unroll
        for (int j = 0; j <= MAX_NGH; ++j) {
            _Float16 wh = (_Float16)(miu[j] * inv);
            h2 wv = {wh, wh};
            a0 += wv * bc2(cv[j].x);
            a1 += wv * bc2(cv[j].y);
            a2 += wv * bc2(cv[j].z);
            a3 += wv * bc2(cv[j].w);
        }

        *(uint4*)&hsh[buf][rl * 136 + l8 * 8]      = rv[0];
        uint4 av = {cb2(a0), cb2(a1), cb2(a2), cb2(a3)};
        *(uint4*)&hsh[buf][rl * 136 + 64 + l8 * 8] = av;

        __syncthreads();

        f32x4 acc0 = {0.f, 0.f, 0.f, 0.f}, acc1 = acc0;
#pragma unroll
        for (int ks = 0; ks < 4; ++ks) {
            h8 af = *(const h8*)&hsh[buf][(r0 + m) * 136 + ks * 32 + q * 8];
            acc0 = __builtin_amdgcn_mfma_f32_16x16x32_f16(af, bf[2 * ks],     acc0, 0, 0, 0);
            acc1 = __builtin_amdgcn_mfma_f32_16x16x32_f16(af, bf[2 * ks + 1], acc1, 0, 0, 0);
        }

        // C layout: col = lane&15, row = quad*4 + reg
        const int gr0 = t * 32 + r0 + q * 4;
#pragma unroll
        for (int tt = 0; tt < 2; ++tt) {
            f32x4 acc = tt ? acc1 : acc0;
            float bv  = tt ? bv1 : bv0;
            int d = ch * 32 + tt * 16 + m;
#pragma unroll
            for (int i = 0; i < 4; ++i) {
                float v = acc[i] + bv;
                v = v > 0.f ? v : (__expf(v) - 1.f);
                __builtin_nontemporal_store(v, &out[(gr0 + i) * 64 + d]);
            }
        }
        buf ^= 1;
    }
}

extern "C" void kernel_launch(void* const* d_in, const int* in_sizes, int n_in,
                              void* d_out, int out_size, void* d_ws, size_t ws_size,
                              hipStream_t stream) {
    const float* cate_emb  = (const float*)d_in[1];
    const float* scene_emb = (const float*)d_in[2];
    const int*   csp       = (const int*)d_in[3];
    const int*   ccp       = (const int*)d_in[4];
    const float* W         = (const float*)d_in[5];
    const float* bias      = (const float*)d_in[6];

    // ws: Wb 16384 | nrm 400000 | rs_h 12,800,000 | cate_h 12,800,000 = 26,016,384 B
    char* ws = (char*)d_ws;
    h8*    Wb     = (h8*)ws;
    float* nrm    = (float*)(ws + 16384);
    h4*    rs_h   = (h4*)(ws + 16384 + 400000);
    h4*    cate_h = (h4*)(ws + 16384 + 400000 + 12800000);
    float* out    = (float*)d_out;

    build_kernel<<<6251, 512, 0, stream>>>(W, cate_emb, scene_emb, csp,
                                           cate_h, rs_h, nrm, Wb);
    main_kernel <<<1024, 256, 0, stream>>>((const uint4*)rs_h, (const uint4*)cate_h,
                                           nrm, (const int2*)ccp, Wb, bias, out);
}

// Round 8
// 158.941 us; speedup vs baseline: 1.0935x; 1.0935x over previous
//
#include <hip/hip_runtime.h>

#define NROWS      100000
#define NUM_CATES  100000
#define MAX_NGH    16
#define MAX_SCENES 10
#define EPSF       1e-10f
#define NTILES     3125

typedef float4 f4;
typedef _Float16 h2 __attribute__((ext_vector_type(2)));
typedef _Float16 h4 __attribute__((ext_vector_type(4)));
typedef _Float16 h8 __attribute__((ext_vector_type(8)));
typedef float f32x4 __attribute__((ext_vector_type(4)));

#if __has_builtin(__builtin_amdgcn_fdot2)
#define FDOT2(a, b, c) __builtin_amdgcn_fdot2((a), (b), (c), false)
#else
#define FDOT2(a, b, c) (fmaf((float)(a).x, (float)(b).x, fmaf((float)(a).y, (float)(b).y, (c))))
#endif

#if __has_builtin(__builtin_amdgcn_rcpf)
#define FRCP(x) __builtin_amdgcn_rcpf(x)
#else
#define FRCP(x) (1.0f / (x))
#endif

__device__ __forceinline__ h2 bc2(unsigned int u) { return __builtin_bit_cast(h2, u); }
__device__ __forceinline__ unsigned int cb2(h2 v) { return __builtin_bit_cast(unsigned int, v); }

// ---- fused build: every block overlaps streaming convert with latency-bound rowsum ----
// block b: converts cate_emb f4-slice [b*512, b*512+512) AND rowsums rows [b*32, b*32+32).
// block 0 additionally packs W into MFMA B-fragment order.
__global__ __launch_bounds__(512) void build_kernel(
    const float* __restrict__ W,          // [64,128]
    const float* __restrict__ cate_emb,   // [N,64] f32
    const float* __restrict__ scene_emb,  // [5001,64] f32
    const int*   __restrict__ csp,        // [N,10]
    h4*          __restrict__ cate_h,     // [N*16] h4
    h4*          __restrict__ rs_h,       // [N*16] h4
    float*       __restrict__ nrm,        // [N]
    h8*          __restrict__ Wb)         // [1024] h8 fragments
{
    const int b = blockIdx.x, tid = threadIdx.x;
    const int lane = tid & 63;
    const int l16  = lane & 15;
    const int row  = b * 32 + (tid >> 6) * 4 + (lane >> 4);   // 32 rows/block, exact

    // issue streaming convert load first (independent of everything)
    const int ci = b * 512 + tid;                  // 3125*512 = 1,600,000 f4 exact
    f4 cval = ((const f4*)cate_emb)[ci];

    // issue rowsum gather chain (csp -> 10 scene gathers, L2-resident table)
    int sidx = csp[row * MAX_SCENES + (l16 < 9 ? l16 : 9)];
    const f4* scene4 = (const f4*)scene_emb;
    f4 a[MAX_SCENES];
#pragma unroll
    for (int k = 0; k < MAX_SCENES; ++k)
        a[k] = scene4[__shfl(sidx, k, 16) * 16 + l16];

    // consume convert while gathers fly
    h4 co = {(_Float16)cval.x, (_Float16)cval.y, (_Float16)cval.z, (_Float16)cval.w};
    cate_h[ci] = co;

    // consume gathers
    f4 s = {0.f, 0.f, 0.f, 0.f};
#pragma unroll
    for (int k = 0; k < MAX_SCENES; ++k) {
        s.x += a[k].x; s.y += a[k].y; s.z += a[k].z; s.w += a[k].w;
    }
    float n2 = s.x * s.x + s.y * s.y + s.z * s.z + s.w * s.w;
#pragma unroll
    for (int off = 1; off < 16; off <<= 1) n2 += __shfl_xor(n2, off);

    h4 hv = {(_Float16)s.x, (_Float16)s.y, (_Float16)s.z, (_Float16)s.w};
    rs_h[row * 16 + l16] = hv;
    if (l16 == 0) nrm[row] = n2;

    if (b == 0) {
        // B-fragment pack: lane l of fragment u holds W[d][k], d = ch*32+t*16+(l&15),
        // k = ks*32 + (l>>4)*8 + j   (16x16x32 f16 B layout: n=lane&15, k=quad*8+j)
#pragma unroll
        for (int u = tid; u < 1024; u += 512) {
            int l  = u & 63;
            int t  = (u >> 6) & 1;
            int ks = (u >> 7) & 3;
            int ch = (u >> 9) & 1;
            int d  = ch * 32 + t * 16 + (l & 15);
            int k0 = ks * 32 + (l >> 4) * 8;
            h8 f;
#pragma unroll
            for (int j = 0; j < 8; ++j) f[j] = (_Float16)W[d * 128 + k0 + j];
            Wb[u] = f;
        }
    }
}

// ---- main: 8 lanes/row sim+agg, MFMA dense, ELU (r6 structure) ----
__global__ __launch_bounds__(256, 4) void main_kernel(
    const uint4* __restrict__ rs4,        // rs_h as [N*8] uint4
    const uint4* __restrict__ cate4,      // cate_h as [N*8] uint4
    const float* __restrict__ nrm,        // [N]
    const int2*  __restrict__ ccp2,       // ccp as [N*8] int2
    const h8*    __restrict__ Wb,         // [1024]
    const float* __restrict__ bias,       // [64]
    float*       __restrict__ out)        // [N,64]
{
    __shared__ _Float16 hsh[32 * 136];    // 32 rows x 128 halves, stride 136

    const int tid  = threadIdx.x;
    const int wave = tid >> 6;
    const int lane = tid & 63;
    const int l8   = lane & 7;
    const int rl   = wave * 8 + (lane >> 3);      // local row 0..31
    const int row  = blockIdx.x * 32 + rl;        // 3125 blocks exact
    const int ch   = wave & 1;                    // col half (32 dims)
    const int r0   = (wave >> 1) * 16;            // local row base of MFMA slab
    const int m    = lane & 15, q = lane >> 4;

    // hoisted invariants: B-fragments + bias (L2-hot; latency hides under gather phase)
    h8 bf[8];
#pragma unroll
    for (int ks = 0; ks < 4; ++ks) {
        bf[2 * ks]     = Wb[((ch * 4 + ks) * 2 + 0) * 64 + lane];
        bf[2 * ks + 1] = Wb[((ch * 4 + ks) * 2 + 1) * 64 + lane];
    }
    const float bv0 = bias[ch * 32 + m];
    const float bv1 = bias[ch * 32 + 16 + m];

    // neighbor ids: lane l8 holds neighbors 2*l8, 2*l8+1 of its row
    int2 nn = ccp2[row * 8 + l8];
    int idx[1 + MAX_NGH];
    idx[0] = row;
#pragma unroll
    for (int j = 1; j <= MAX_NGH; ++j)
        idx[j] = __shfl((j & 1) ? nn.x : nn.y, (j - 1) >> 1, 8);

    // batch rs gathers: 17 x b128, each serves 8 rows of the wave
    uint4 rv[1 + MAX_NGH];
#pragma unroll
    for (int j = 0; j <= MAX_NGH; ++j) rv[j] = rs4[idx[j] * 8 + l8];

    float m0 = nrm[nn.x], m1 = nrm[nn.y];
    float ns = nrm[row] + EPSF;
    float ns_inv = FRCP(ns);

    h2 s0 = bc2(rv[0].x), s1 = bc2(rv[0].y), s2 = bc2(rv[0].z), s3 = bc2(rv[0].w);

    // partial dots (consume rv as they arrive)
    float dotp[1 + MAX_NGH];
#pragma unroll
    for (int j = 0; j <= MAX_NGH; ++j) {
        dotp[j] = FDOT2(s0, bc2(rv[j].x),
                  FDOT2(s1, bc2(rv[j].y),
                  FDOT2(s2, bc2(rv[j].z),
                  FDOT2(s3, bc2(rv[j].w), 0.f))));
    }

    // issue cate gathers now so they fly during reduce/exp
    uint4 cv[1 + MAX_NGH];
#pragma unroll
    for (int j = 0; j <= MAX_NGH; ++j) cv[j] = cate4[idx[j] * 8 + l8];

    float miu[1 + MAX_NGH];
    float summiu = 0.f;
#pragma unroll
    for (int j = 0; j <= MAX_NGH; ++j) {
        float d = dotp[j];
        d += __shfl_xor(d, 1); d += __shfl_xor(d, 2); d += __shfl_xor(d, 4);
        float rr = (j == 0) ? (ns - EPSF) : __shfl((j & 1) ? m0 : m1, (j - 1) >> 1, 8);
        bool msk = idx[j] < (NUM_CATES - 1);
        float mu = msk ? __expf(d * ns_inv * FRCP(rr + EPSF)) : 0.f;
        miu[j] = mu;
        summiu += mu;
    }

    const float inv = FRCP(summiu + EPSF);
    const _Float16 z16 = (_Float16)0.f;
    h2 a0 = {z16, z16}, a1 = a0, a2 = a0, a3 = a0;
#pragma unroll
    for (int j = 0; j <= MAX_NGH; ++j) {
        _Float16 wh = (_Float16)(miu[j] * inv);
        h2 wv = {wh, wh};
        a0 += wv * bc2(cv[j].x);
        a1 += wv * bc2(cv[j].y);
        a2 += wv * bc2(cv[j].z);
        a3 += wv * bc2(cv[j].w);
    }

    // h = [s | agg] into LDS, b128 writes
    *(uint4*)&hsh[rl * 136 + l8 * 8]      = rv[0];
    uint4 av = {cb2(a0), cb2(a1), cb2(a2), cb2(a3)};
    *(uint4*)&hsh[rl * 136 + 64 + l8 * 8] = av;

    __syncthreads();

    // out[32x64] = h[32x128] x W^T via 16x16x32 f16 MFMA; wave does 16 rows x 32 cols
    f32x4 acc0 = {0.f, 0.f, 0.f, 0.f}, acc1 = acc0;
#pragma unroll
    for (int ks = 0; ks < 4; ++ks) {
        h8 af = *(const h8*)&hsh[(r0 + m) * 136 + ks * 32 + q * 8];
        acc0 = __builtin_amdgcn_mfma_f32_16x16x32_f16(af, bf[2 * ks],     acc0, 0, 0, 0);
        acc1 = __builtin_amdgcn_mfma_f32_16x16x32_f16(af, bf[2 * ks + 1], acc1, 0, 0, 0);
    }

    // C layout: col = lane&15, row = quad*4 + reg
    const int gr0 = blockIdx.x * 32 + r0 + q * 4;
#pragma unroll
    for (int tt = 0; tt < 2; ++tt) {
        f32x4 acc = tt ? acc1 : acc0;
        float bv  = tt ? bv1 : bv0;
        int d = ch * 32 + tt * 16 + m;
#pragma unroll
        for (int i = 0; i < 4; ++i) {
            float v = acc[i] + bv;
            v = v > 0.f ? v : (__expf(v) - 1.f);
            out[(gr0 + i) * 64 + d] = v;
        }
    }
}

extern "C" void kernel_launch(void* const* d_in, const int* in_sizes, int n_in,
                              void* d_out, int out_size, void* d_ws, size_t ws_size,
                              hipStream_t stream) {
    const float* cate_emb  = (const float*)d_in[1];
    const float* scene_emb = (const float*)d_in[2];
    const int*   csp       = (const int*)d_in[3];
    const int*   ccp       = (const int*)d_in[4];
    const float* W         = (const float*)d_in[5];
    const float* bias      = (const float*)d_in[6];

    // ws: Wb 16384 | nrm 400000 | rs_h 12,800,000 | cate_h 12,800,000 = 26,016,384 B
    char* ws = (char*)d_ws;
    h8*    Wb     = (h8*)ws;
    float* nrm    = (float*)(ws + 16384);
    h4*    rs_h   = (h4*)(ws + 16384 + 400000);
    h4*    cate_h = (h4*)(ws + 16384 + 400000 + 12800000);
    float* out    = (float*)d_out;

    build_kernel<<<NTILES, 512, 0, stream>>>(W, cate_emb, scene_emb, csp,
                                             cate_h, rs_h, nrm, Wb);
    main_kernel <<<NTILES, 256, 0, stream>>>((const uint4*)rs_h, (const uint4*)cate_h,
                                             nrm, (const int2*)ccp, Wb, bias, out);
}